// Round 6
// baseline (342.502 us; speedup 1.0000x reference)
//
#include <hip/hip_runtime.h>
#include <hip/hip_bf16.h>

using u16 = unsigned short;

typedef __bf16 bf16x8 __attribute__((ext_vector_type(8)));
typedef float  f32x4  __attribute__((ext_vector_type(4)));

__device__ __forceinline__ float b2f(u16 u) {
  union { unsigned u; float f; } v; v.u = ((unsigned)u) << 16; return v.f;
}
__device__ __forceinline__ u16 f2b(float f) {
  union { float f; unsigned u; } v; v.f = f;
  unsigned r = v.u + 0x7fffu + ((v.u >> 16) & 1u);
  return (u16)(r >> 16);
}

// async global->LDS, 16B per lane. LDS dest must be uniform base + lane*16.
__device__ __forceinline__ void gld_lds16(const void* g, void* l) {
  __builtin_amdgcn_global_load_lds(
      (__attribute__((address_space(1))) void*)(unsigned long long)(g),
      (__attribute__((address_space(3))) void*)(unsigned long long)(l),
      16, 0, 0);
}

// ---------------------------------------------------------------------------
// Generic NT GEMM: C[m,n] = sum_k A[m,k] * B[n,k], bf16 in, fp32 acc.
// Block tile 128x128, 4 waves (2x2), wave = 4x4 of 16x16x32 MFMA.
// BK=32 for occupancy-sensitive big-grid GEMMs; BK=64 for 1-block/CU GEMMs.
// XOR swizzle keeps ds_read_b128 at 2-way bank aliasing (free, m136).
// Batch via blockIdx.z: zb=z/HDIV, zh=z%HDIV; operand offset = zb*s1 + zh*s2.
// EPI: 0 = write bf16 (used by split-K proj: zb = k-half, zh = tensor);
//      1 = kv GEMM: write bf16 AND atomicAdd per-column tile sums into
//          partOut[zh*256 + col] (cs head-mean fusion; partOut pre-zeroed);
//      2 = causal A-GEMM: grid x in {0,1,2} remapped to (bx,by) in
//          {(0,0),(0,1),(1,1)}, mask col<=row -> bf16;
//      3 = A@V: K clamped to (by+1)*128; den = rowsum(A) from A-fragments
//          in-register (shfl + LDS broadcast); write bf16 of v/den;
//      4 = split-K Wo: zb==0 writes v+bias[col]+resid, zb==1 writes v (fp32)
//          zb=1 dest = Cv + sC1 (must match kernel_launch layout!)
// ---------------------------------------------------------------------------
template <int EPI, int BK>
__global__ __launch_bounds__(256) void gemm_bt(
    const u16* __restrict__ A, int lda, long sA1, long sA2,
    const u16* __restrict__ B, int ldb, long sB1, long sB2,
    void* __restrict__ Cv, int ldc, long sC1, long sC2,
    int K, int HDIV,
    const float* __restrict__ bias, const float* __restrict__ resid,
    float* __restrict__ partOut) {
  __shared__ __align__(16) u16 lds[2 * 128 * BK];
  __shared__ float denS[128];
  const int t = threadIdx.x;
  const int lane = t & 63;
  const int wave = t >> 6;
  const int wm = wave >> 1, wn = wave & 1;
  const int laneM = lane & 15, quad = lane >> 4;
  const int zb = blockIdx.z / HDIV, zh = blockIdx.z % HDIV;

  int bx = blockIdx.x, by = blockIdx.y;
  if (EPI == 2) { by = (bx >= 1) ? 1 : 0; bx = (bx == 2) ? 1 : 0; }
  const int kEnd = (EPI == 3) ? ((by + 1) * 128 < K ? (by + 1) * 128 : K) : K;

  const u16* Abase = A + zb * sA1 + zh * sA2 + (long)by * 128 * lda;
  const u16* Bbase = B + zb * sB1 + zh * sB2 + (long)bx * 128 * ldb;

  constexpr int STEPS = BK / 16;   // staging steps per operand (2048 elem each)
  constexpr int RPS = 2048 / BK;   // rows per staging step
  constexpr int KK = BK / 32;      // MFMA k-steps per LDS tile
  const int sRow = (BK == 64) ? (t >> 3) : (t >> 2);
  const int sg = (BK == 64) ? (t & 7) : (t & 3);
  const int swz = (BK == 64) ? (sg ^ (sRow & 7)) : (sg ^ ((sRow >> 1) & 3));
  const int sc = swz * 8;  // swizzled global k-chunk offset (elems)

  f32x4 acc[4][4];
#pragma unroll
  for (int i = 0; i < 4; ++i)
#pragma unroll
    for (int j = 0; j < 4; ++j) acc[i][j] = (f32x4){0.f, 0.f, 0.f, 0.f};
  float dsum[4] = {0.f, 0.f, 0.f, 0.f};

  for (int k0 = 0; k0 < kEnd; k0 += BK) {
#pragma unroll
    for (int p = 0; p < STEPS; ++p)
      gld_lds16(Abase + (long)(p * RPS + sRow) * lda + k0 + sc,
                &lds[p * 2048 + t * 8]);
#pragma unroll
    for (int p = 0; p < STEPS; ++p)
      gld_lds16(Bbase + (long)(p * RPS + sRow) * ldb + k0 + sc,
                &lds[128 * BK + p * 2048 + t * 8]);
    __syncthreads();  // drains vmcnt(0): LDS staging complete
    bf16x8 af[KK][4], bfv[KK][4];
#pragma unroll
    for (int kk = 0; kk < KK; ++kk) {
      int perm8;
      if (BK == 64) perm8 = ((kk * 4 + quad) ^ (laneM & 7)) * 8;
      else          perm8 = (quad ^ ((laneM >> 1) & 3)) * 8;
#pragma unroll
      for (int i = 0; i < 4; ++i) {
        af[kk][i] = *(const bf16x8*)&lds[(wm * 64 + i * 16 + laneM) * BK + perm8];
        bfv[kk][i] =
            *(const bf16x8*)&lds[128 * BK + (wn * 64 + i * 16 + laneM) * BK + perm8];
      }
    }
    if (EPI == 3) {  // rowsum of A from fragments (den; mask is pre-applied)
#pragma unroll
      for (int kk = 0; kk < KK; ++kk)
#pragma unroll
        for (int i = 0; i < 4; ++i) {
          union { bf16x8 v; u16 s[8]; } u; u.v = af[kk][i];
          float ds = 0.f;
#pragma unroll
          for (int e = 0; e < 8; ++e) ds += b2f(u.s[e]);
          dsum[i] += ds;
        }
    }
#pragma unroll
    for (int kk = 0; kk < KK; ++kk)
#pragma unroll
      for (int i = 0; i < 4; ++i)
#pragma unroll
        for (int j = 0; j < 4; ++j)
          acc[i][j] = __builtin_amdgcn_mfma_f32_16x16x32_bf16(
              af[kk][i], bfv[kk][j], acc[i][j], 0, 0, 0);
    __syncthreads();  // all waves done reading before next stage
  }

  if (EPI == 3) {
#pragma unroll
    for (int i = 0; i < 4; ++i) {
      float s = dsum[i];
      s += __shfl_xor(s, 16);
      s += __shfl_xor(s, 32);
      if (wn == 0 && quad == 0)
        denS[wm * 64 + i * 16 + laneM] = fmaxf(s, 1e-8f);
    }
    __syncthreads();
  }

  if (EPI == 1) {  // column sums of tile -> part[zh*256 + col] (cs fusion)
#pragma unroll
    for (int j = 0; j < 4; ++j) {
      float s = 0.f;
#pragma unroll
      for (int i = 0; i < 4; ++i)
#pragma unroll
        for (int r = 0; r < 4; ++r) s += acc[i][j][r];
      s += __shfl_xor(s, 16);
      s += __shfl_xor(s, 32);
      if (quad == 0)
        atomicAdd(&partOut[zh * 256 + bx * 128 + wn * 64 + j * 16 + laneM], s);
    }
  }

  const long cOff = zb * sC1 + zh * sC2;
  const int colB = bx * 128 + wn * 64;
#pragma unroll
  for (int i = 0; i < 4; ++i) {
#pragma unroll
    for (int j = 0; j < 4; ++j) {
#pragma unroll
      for (int r = 0; r < 4; ++r) {
        const int lrow = wm * 64 + i * 16 + quad * 4 + r;  // row within block
        const int row = by * 128 + lrow;                   // within-batch row
        const int col = colB + j * 16 + laneM;             // within-batch col
        const long idx = cOff + (long)row * ldc + col;
        float v = acc[i][j][r];
        if (EPI == 0 || EPI == 1) {
          ((u16*)Cv)[idx] = f2b(v);
        } else if (EPI == 2) {
          ((u16*)Cv)[idx] = f2b(col <= row ? v : 0.0f);
        } else if (EPI == 3) {
          ((u16*)Cv)[idx] = f2b(v / denS[lrow]);
        } else {
          ((float*)Cv)[idx] =
              (zb == 0) ? v + bias[col] + resid[(long)row * ldc + col] : v;
        }
      }
    }
  }
}

// ---------------------------------------------------------------------------
// Convert 7 fp32 2048x2048 tensors -> bf16, dsts contiguous from dst base.
// ---------------------------------------------------------------------------
__global__ __launch_bounds__(256) void convert7(
    const float* __restrict__ s0, const float* __restrict__ s1,
    const float* __restrict__ s2, const float* __restrict__ s3,
    const float* __restrict__ s4, const float* __restrict__ s5,
    const float* __restrict__ s6, u16* __restrict__ dst) {
  long idx = (long)blockIdx.x * 256 + threadIdx.x;  // 0 .. 7*1048576-1
  int seg = (int)(idx >> 20);
  long off = (idx & 1048575) << 2;
  const float* s;
  switch (seg) {
    case 0: s = s0; break; case 1: s = s1; break; case 2: s = s2; break;
    case 3: s = s3; break; case 4: s = s4; break; case 5: s = s5; break;
    default: s = s6;
  }
  float4 v = *(const float4*)(s + off);
  ushort4 o;
  o.x = f2b(v.x); o.y = f2b(v.y); o.z = f2b(v.z); o.w = f2b(v.w);
  *(ushort4*)(dst + (long)seg * 4194304 + off) = o;
}

// K = K0 + K1 elementwise (bf16), 4 elems/thread.
__global__ __launch_bounds__(256) void reduce_add(
    const u16* __restrict__ a, const u16* __restrict__ b,
    u16* __restrict__ o) {
  long i = ((long)blockIdx.x * 256 + threadIdx.x) * 4;
  ushort4 x = *(const ushort4*)&a[i];
  ushort4 y = *(const ushort4*)&b[i];
  ushort4 r;
  r.x = f2b(b2f(x.x) + b2f(y.x));
  r.y = f2b(b2f(x.y) + b2f(y.y));
  r.z = f2b(b2f(x.z) + b2f(y.z));
  r.w = f2b(b2f(x.w) + b2f(y.w));
  *(ushort4*)&o[i] = r;
}

// Vp = V0+V1; Vt[b,h,d,j] = Vp[b*256+j, h*256+d] (sum + per-(b,h) transpose)
__global__ __launch_bounds__(256) void reduceV_kernel(
    const u16* __restrict__ V0, const u16* __restrict__ V1,
    u16* __restrict__ Vp, u16* __restrict__ Vt) {
  __shared__ u16 tile[32][33];
  int z = blockIdx.z, b = z >> 3, h = z & 7;
  int jT = blockIdx.x * 32, dT = blockIdx.y * 32;
  int tx = threadIdx.x, ty = threadIdx.y;  // (32, 8)
#pragma unroll
  for (int ii = 0; ii < 4; ++ii) {
    int j = jT + ty + ii * 8, d = dT + tx;
    long src = (long)(b * 256 + j) * 2048 + h * 256 + d;
    u16 s = f2b(b2f(V0[src]) + b2f(V1[src]));
    tile[ty + ii * 8][tx] = s;
    Vp[src] = s;
  }
  __syncthreads();
#pragma unroll
  for (int ii = 0; ii < 4; ++ii) {
    int d = dT + ty + ii * 8, j = jT + tx;
    Vt[(long)z * 65536 + d * 256 + j] = tile[tx][ty + ii * 8];
  }
}

// pq = phi(Q*(cs+alpha*(kv-cs))), pk = phi(K); phi(x)=x>0?x+1:exp(x).
// Q = Q0+Q1 (split-K partials summed here). cs scan (h<=7 steps over the
// 8x256 'part' head-sums) computed in-kernel: h is uniform per block.
// 4 elems (consecutive d) per thread.
__global__ __launch_bounds__(256) void pqpk_kernel(
    const u16* __restrict__ Q0, const u16* __restrict__ Q1,
    const u16* __restrict__ Kp, const u16* __restrict__ kv,
    const float* __restrict__ part, const float* __restrict__ alphaP,
    const float* __restrict__ betaP, u16* __restrict__ pq,
    u16* __restrict__ pk) {
  long e = ((long)blockIdx.x * 256 + threadIdx.x) * 4;  // (b,h,l,d) packed
  int d = (int)(e & 255), l = (int)((e >> 8) & 255), h = (int)((e >> 16) & 7),
      b = (int)(e >> 19);
  float alpha = *alphaP, beta = *betaP;
  float4 c = {0.f, 0.f, 0.f, 0.f};
  for (int hh = 0; hh < h; ++hh) {  // h uniform per block (block = one l-row/4)
    float4 p = *(const float4*)&part[hh * 256 + d];
    c.x = beta * c.x + alpha * (p.x * (1.0f / 2048.0f));
    c.y = beta * c.y + alpha * (p.y * (1.0f / 2048.0f));
    c.z = beta * c.z + alpha * (p.z * (1.0f / 2048.0f));
    c.w = beta * c.w + alpha * (p.w * (1.0f / 2048.0f));
  }
  long pidx = ((long)(b * 256 + l)) * 2048 + h * 256 + d;
  ushort4 q0 = *(const ushort4*)&Q0[pidx];
  ushort4 q1 = *(const ushort4*)&Q1[pidx];
  ushort4 kk = *(const ushort4*)&Kp[pidx];
  ushort4 kvv = *(const ushort4*)&kv[e];
  ushort4 opq, opk;
#define PQPK1(comp)                                                    \
  {                                                                    \
    float Qv = b2f(q0.comp) + b2f(q1.comp);                            \
    float qm = Qv * (c.comp + alpha * (b2f(kvv.comp) - c.comp));       \
    opq.comp = f2b(qm > 0.f ? qm + 1.f : expf(qm));                    \
    float Kv = b2f(kk.comp);                                           \
    opk.comp = f2b(Kv > 0.f ? Kv + 1.f : expf(Kv));                    \
  }
  PQPK1(x) PQPK1(y) PQPK1(z) PQPK1(w)
#undef PQPK1
  *(ushort4*)&pq[e] = opq;
  *(ushort4*)&pk[e] = opk;
}

// LayerNorm over rows of 2048; input = x0 + x1 (split-K partials).
__global__ __launch_bounds__(256) void ln_kernel(
    const float* __restrict__ x0, const float* __restrict__ x1,
    const float* __restrict__ g, const float* __restrict__ bb,
    float* __restrict__ out) {
  int row = blockIdx.x, t = threadIdx.x;
  const float4* xr0 = (const float4*)(x0 + (long)row * 2048);
  const float4* xr1 = (const float4*)(x1 + (long)row * 2048);
  float4 a0 = xr0[t], b0 = xr1[t], a1 = xr0[t + 256], b1 = xr1[t + 256];
  float4 v0, v1;
  v0.x = a0.x + b0.x; v0.y = a0.y + b0.y; v0.z = a0.z + b0.z; v0.w = a0.w + b0.w;
  v1.x = a1.x + b1.x; v1.y = a1.y + b1.y; v1.z = a1.z + b1.z; v1.w = a1.w + b1.w;
  float s = v0.x + v0.y + v0.z + v0.w + v1.x + v1.y + v1.z + v1.w;
  float ss = v0.x * v0.x + v0.y * v0.y + v0.z * v0.z + v0.w * v0.w +
             v1.x * v1.x + v1.y * v1.y + v1.z * v1.z + v1.w * v1.w;
  for (int o = 32; o; o >>= 1) { s += __shfl_xor(s, o); ss += __shfl_xor(ss, o); }
  __shared__ float a1s[4], a2s[4];
  int wave = t >> 6, lane = t & 63;
  if (lane == 0) { a1s[wave] = s; a2s[wave] = ss; }
  __syncthreads();
  s = a1s[0] + a1s[1] + a1s[2] + a1s[3];
  ss = a2s[0] + a2s[1] + a2s[2] + a2s[3];
  float mu = s * (1.f / 2048.f);
  float var = ss * (1.f / 2048.f) - mu * mu;
  float rstd = rsqrtf(var + 1e-5f);
  const float4* g4 = (const float4*)g;
  const float4* b4 = (const float4*)bb;
  float4* orow = (float4*)(out + (long)row * 2048);
  float4 gg = g4[t], bv = b4[t], r;
  r.x = (v0.x - mu) * rstd * gg.x + bv.x;
  r.y = (v0.y - mu) * rstd * gg.y + bv.y;
  r.z = (v0.z - mu) * rstd * gg.z + bv.z;
  r.w = (v0.w - mu) * rstd * gg.w + bv.w;
  orow[t] = r;
  gg = g4[t + 256]; bv = b4[t + 256];
  r.x = (v1.x - mu) * rstd * gg.x + bv.x;
  r.y = (v1.y - mu) * rstd * gg.y + bv.y;
  r.z = (v1.z - mu) * rstd * gg.z + bv.z;
  r.w = (v1.w - mu) * rstd * gg.w + bv.w;
  orow[t + 256] = r;
}

extern "C" void kernel_launch(void* const* d_in, const int* in_sizes, int n_in,
                              void* d_out, int out_size, void* d_ws,
                              size_t ws_size, hipStream_t stream) {
  const float* query = (const float*)d_in[0];
  const float* key = (const float*)d_in[1];
  const float* value = (const float*)d_in[2];
  const float* Wq = (const float*)d_in[3];
  const float* Wk = (const float*)d_in[4];
  const float* Wv = (const float*)d_in[5];
  const float* Wo = (const float*)d_in[6];
  const float* bo = (const float*)d_in[7];
  const float* ln_g = (const float*)d_in[8];
  const float* ln_b = (const float*)d_in[9];
  const float* alphaP = (const float*)d_in[10];
  const float* betaP = (const float*)d_in[11];

  char* ws = (char*)d_ws;
  const long SZ = 8388608;        // bytes of one 2048x2048 bf16 tensor
  const long SE = 4194304;        // elements of one 2048x2048 tensor
  // Workspace timeline (liveness checked against dispatch order):
  //  @0  (3 SZ) qb: q,k,v bf16 inputs      -> dead after proj; Vt reuses @0
  //  @3  (4 SZ) Wb: Wq,Wk,Wv,Wo bf16       -> Wq/Wk/Wv dead after proj
  //             (pq reuses @3, pk @4, attnb @5); Wob @6 lives until Wo GEMM
  //  @7  (6 SZ) P: proj split-K partials Q0,K0,V0 (half0) Q1,K1,V1 (half1)
  //             K0/V0 dead after reduces -> x0 reuses @8 (2 SZ fp32)
  //             Q1 dead after pqpk       -> x1 reuses @10 (2 SZ fp32)
  //  @13 (1 SZ) Kp = K0+K1;  @14 (1 SZ) Vp = V0+V1
  //  @1  (1 SZ) kvb (kv bf16), later Ab (A matrix) overwrites it
  //  @15 part (8 KB, atomic-accumulated head sums)
  u16* qb = (u16*)(ws);
  u16* Wb = (u16*)(ws + 3 * SZ);
  u16* P = (u16*)(ws + 7 * SZ);
  u16* Q0 = P;                    // half 0: Q0,K0,V0
  u16* K0 = P + 1 * SE;
  u16* V0 = P + 2 * SE;
  u16* Q1 = P + 3 * SE;           // half 1: Q1,K1,V1
  u16* K1 = P + 4 * SE;
  u16* V1 = P + 5 * SE;
  u16* Kp = (u16*)(ws + 13 * SZ);
  u16* Vp = (u16*)(ws + 14 * SZ);
  u16* Vt = (u16*)(ws);           // reuses qb (dead after proj)
  u16* kvb = (u16*)(ws + 1 * SZ); // reuses k-input (dead after proj)
  u16* Ab = kvb;                  // reuses kvb (dead after pqpk)
  u16* pq = (u16*)(ws + 3 * SZ);  // reuses Wq (dead after proj)
  u16* pk = (u16*)(ws + 4 * SZ);  // reuses Wk
  u16* attnb = (u16*)(ws + 5 * SZ);  // reuses Wv
  u16* Wob = Wb + 3 * SE;         // @6, preserved until Wo GEMM
  float* x0 = (float*)(ws + 8 * SZ);   // reuses K0,V0 (dead after reduces)
  float* x1 = (float*)(ws + 10 * SZ);  // reuses Q1,K1 (dead after pqpk)
  float* part = (float*)(ws + 15 * SZ);

  // 0. zero the cs partial-sum accumulator (d_ws is re-poisoned every call)
  hipMemsetAsync(part, 0, 8 * 256 * sizeof(float), stream);

  // 1. fp32 -> bf16 converts (7 tensors)
  convert7<<<28672, 256, 0, stream>>>(query, key, value, Wq, Wk, Wv, Wo, qb);

  // 2. Q/K/V projections, split-K=2: z = half*3 + tensor (HDIV=3).
  //    6 blocks/CU (1536 blocks) vs 3 for unsplit -- hides barrier drain.
  gemm_bt<0, 32><<<dim3(16, 16, 6), 256, 0, stream>>>(
      qb, 2048, 1024L, (long)SE, Wb, 2048, 1024L, (long)SE, (void*)P, 2048,
      3 * SE, SE, 1024, 3, nullptr, nullptr, nullptr);

  // 3. Kp = K0+K1 (kv GEMM + pqpk consumer)
  reduce_add<<<4096, 256, 0, stream>>>(K0, K1, Kp);

  // 4. Vp = V0+V1 and Vt = per-(b,h) transpose (absorbs old vtrans)
  reduceV_kernel<<<dim3(8, 8, 64), dim3(32, 8), 0, stream>>>(V0, V1, Vp, Vt);

  // 5. kv[b,h,l,m] = sum_d K[b,h,l,d] V[b,h,m,d] (64 batches, bf16 out)
  //    + fused column sums into part[h*256+m] via atomics
  gemm_bt<1, 64><<<dim3(2, 2, 64), 256, 0, stream>>>(
      Kp, 2048, 524288L, 256L, Vp, 2048, 524288L, 256L, (void*)kvb, 256,
      524288L, 65536L, 256, 8, nullptr, nullptr, part);

  // 6. pq/pk with in-kernel cs scan; Q = Q0+Q1 summed here
  pqpk_kernel<<<4096, 256, 0, stream>>>(Q0, Q1, Kp, kvb, part, alphaP, betaP,
                                        pq, pk);

  // 7. A = pq @ pk^T, causal-masked, bf16 (overwrites kvb).
  //    Fully-masked block (x=1,y=0) skipped: 3 xy-blocks per batch.
  gemm_bt<2, 64><<<dim3(3, 1, 64), 256, 0, stream>>>(
      pq, 256, 524288L, 65536L, pk, 256, 524288L, 65536L, (void*)Ab, 256,
      524288L, 65536L, 256, 8, nullptr, nullptr, nullptr);

  // 8. attn = (A @ V) / den, den fused from A-fragments, K clamped causally
  gemm_bt<3, 64><<<dim3(2, 2, 64), 256, 0, stream>>>(
      Ab, 256, 524288L, 65536L, Vt, 256, 524288L, 65536L, (void*)attnb, 2048,
      524288L, 256L, 256, 8, nullptr, nullptr, nullptr);

  // 9. x = attn @ Wo^T (+ bo + query on z=0), split-K=2 -> x0 (@8SZ), x1 (@10SZ)
  //    sC1 = (x1 - x0) in floats = 2*SZ/4 = SE
  gemm_bt<4, 32><<<dim3(16, 16, 2), 256, 0, stream>>>(
      attnb, 2048, 1024L, 0L, Wob, 2048, 1024L, 0L, (void*)x0, 2048, (long)SE,
      0L, 1024, 1, bo, query, nullptr);

  // 10. LayerNorm(x0 + x1) -> d_out
  ln_kernel<<<2048, 256, 0, stream>>>(x0, x1, ln_g, ln_b, (float*)d_out);
}

// Round 7
// 332.351 us; speedup vs baseline: 1.0305x; 1.0305x over previous
//
#include <hip/hip_runtime.h>
#include <hip/hip_bf16.h>

using u16 = unsigned short;

typedef __bf16 bf16x8 __attribute__((ext_vector_type(8)));
typedef float  f32x4  __attribute__((ext_vector_type(4)));

__device__ __forceinline__ float b2f(u16 u) {
  union { unsigned u; float f; } v; v.u = ((unsigned)u) << 16; return v.f;
}
__device__ __forceinline__ u16 f2b(float f) {
  union { float f; unsigned u; } v; v.f = f;
  unsigned r = v.u + 0x7fffu + ((v.u >> 16) & 1u);
  return (u16)(r >> 16);
}

// async global->LDS, 16B per lane. LDS dest must be uniform base + lane*16.
__device__ __forceinline__ void gld_lds16(const void* g, void* l) {
  __builtin_amdgcn_global_load_lds(
      (__attribute__((address_space(1))) void*)(unsigned long long)(g),
      (__attribute__((address_space(3))) void*)(unsigned long long)(l),
      16, 0, 0);
}

// ---------------------------------------------------------------------------
// Generic NT GEMM: C[m,n] = sum_k A[m,k]*B[n,k], bf16 in, fp32 acc.
// Template: EPI (epilogue), BK (k-tile), TM (output tile = TM x TM).
//   TM=128: 4 waves 2x2, each 4x4 of 16x16x32 MFMA (64 AGPR acc). For the
//     big GEMMs (proj/Wo). 72+64 unified regs -> 3 blocks/CU (R6 lesson:
//     occupancy is register-limited; split-K does NOT help).
//   TM=64: 4 waves 2x2, each 2x2 of 16x16x32 (16 AGPR acc). For the small
//     batched GEMMs (kv/A/AV): 4x the blocks -> 4 blocks/CU = 16 waves/CU
//     of latency hiding where grid previously gave 1 block/CU.
// XOR swizzle keeps ds_read_b128 at 2-way bank aliasing (free, m136).
// Batch via blockIdx.z: zb=z/HDIV, zh=z%HDIV; operand offset = zb*s1 + zh*s2.
// EPI: 0 = write bf16;
//      1 = kv GEMM: write bf16 + atomicAdd per-column tile sums into
//          partOut[zh*256+col] (cs head-mean fusion; partOut pre-zeroed);
//      2 = causal A-GEMM (TM=64): blocks with bx>by exit (upper triangle
//          unwritten AND never read: AV clamps K); mask col<=row -> bf16;
//      3 = A@V: K clamped to (by+1)*TM; den = rowsum(A) from A-fragments
//          (shfl + LDS broadcast); write bf16 of v/den;
//      4 = split-K Wo: zb==0 writes v+bias[col]+resid, zb==1 writes v (fp32)
//          zb=1 dest = Cv + sC1 (must match kernel_launch layout!)
// ---------------------------------------------------------------------------
template <int EPI, int BK, int TM>
__global__ __launch_bounds__(256) void gemm_bt(
    const u16* __restrict__ A, int lda, long sA1, long sA2,
    const u16* __restrict__ B, int ldb, long sB1, long sB2,
    void* __restrict__ Cv, int ldc, long sC1, long sC2,
    int K, int HDIV,
    const float* __restrict__ bias, const float* __restrict__ resid,
    float* __restrict__ partOut) {
  constexpr int WT = TM / 2;       // wave tile
  constexpr int FR = WT / 16;      // frags per dim per wave (4 or 2)
  constexpr int KK = BK / 32;      // MFMA k-steps per LDS tile
  constexpr int STEPS = TM * BK / 2048;  // staging rounds per operand
  constexpr int RPS = 2048 / BK;   // rows per staging round
  __shared__ __align__(16) u16 lds[2 * TM * BK];
  __shared__ float denS[TM];
  const int t = threadIdx.x;
  const int lane = t & 63;
  const int wave = t >> 6;
  const int wm = wave >> 1, wn = wave & 1;
  const int laneM = lane & 15, quad = lane >> 4;
  const int zb = blockIdx.z / HDIV, zh = blockIdx.z % HDIV;

  const int bx = blockIdx.x, by = blockIdx.y;
  if (EPI == 2 && bx > by) return;  // upper-triangle: all-masked, skip
  const int kEnd = (EPI == 3) ? ((by + 1) * TM < K ? (by + 1) * TM : K) : K;

  const u16* Abase = A + zb * sA1 + zh * sA2 + (long)by * TM * lda;
  const u16* Bbase = B + zb * sB1 + zh * sB2 + (long)bx * TM * ldb;

  const int sRow = (BK == 64) ? (t >> 3) : (t >> 2);
  const int sg = (BK == 64) ? (t & 7) : (t & 3);
  const int swz = (BK == 64) ? (sg ^ (sRow & 7)) : (sg ^ ((sRow >> 1) & 3));
  const int sc = swz * 8;  // swizzled global k-chunk offset (elems)

  f32x4 acc[FR][FR];
#pragma unroll
  for (int i = 0; i < FR; ++i)
#pragma unroll
    for (int j = 0; j < FR; ++j) acc[i][j] = (f32x4){0.f, 0.f, 0.f, 0.f};
  float dsum[FR];
#pragma unroll
  for (int i = 0; i < FR; ++i) dsum[i] = 0.f;

  for (int k0 = 0; k0 < kEnd; k0 += BK) {
#pragma unroll
    for (int p = 0; p < STEPS; ++p)
      gld_lds16(Abase + (long)(p * RPS + sRow) * lda + k0 + sc,
                &lds[p * 2048 + t * 8]);
#pragma unroll
    for (int p = 0; p < STEPS; ++p)
      gld_lds16(Bbase + (long)(p * RPS + sRow) * ldb + k0 + sc,
                &lds[TM * BK + p * 2048 + t * 8]);
    __syncthreads();  // drains vmcnt(0): LDS staging complete
    bf16x8 af[KK][FR], bfv[KK][FR];
#pragma unroll
    for (int kk = 0; kk < KK; ++kk) {
      int perm8;
      if (BK == 64) perm8 = ((kk * 4 + quad) ^ (laneM & 7)) * 8;
      else          perm8 = (quad ^ ((laneM >> 1) & 3)) * 8;
#pragma unroll
      for (int i = 0; i < FR; ++i) {
        af[kk][i] = *(const bf16x8*)&lds[(wm * WT + i * 16 + laneM) * BK + perm8];
        bfv[kk][i] =
            *(const bf16x8*)&lds[TM * BK + (wn * WT + i * 16 + laneM) * BK + perm8];
      }
    }
    if (EPI == 3) {  // rowsum of A from fragments (den; mask pre-applied)
#pragma unroll
      for (int kk = 0; kk < KK; ++kk)
#pragma unroll
        for (int i = 0; i < FR; ++i) {
          union { bf16x8 v; u16 s[8]; } u; u.v = af[kk][i];
          float ds = 0.f;
#pragma unroll
          for (int e = 0; e < 8; ++e) ds += b2f(u.s[e]);
          dsum[i] += ds;
        }
    }
#pragma unroll
    for (int kk = 0; kk < KK; ++kk)
#pragma unroll
      for (int i = 0; i < FR; ++i)
#pragma unroll
        for (int j = 0; j < FR; ++j)
          acc[i][j] = __builtin_amdgcn_mfma_f32_16x16x32_bf16(
              af[kk][i], bfv[kk][j], acc[i][j], 0, 0, 0);
    __syncthreads();  // all waves done reading before next stage
  }

  if (EPI == 3) {
#pragma unroll
    for (int i = 0; i < FR; ++i) {
      float s = dsum[i];
      s += __shfl_xor(s, 16);
      s += __shfl_xor(s, 32);
      if (wn == 0 && quad == 0)
        denS[wm * WT + i * 16 + laneM] = fmaxf(s, 1e-8f);
    }
    __syncthreads();
  }

  if (EPI == 1) {  // column sums of tile -> part[zh*256+col] (cs fusion)
#pragma unroll
    for (int j = 0; j < FR; ++j) {
      float s = 0.f;
#pragma unroll
      for (int i = 0; i < FR; ++i)
#pragma unroll
        for (int r = 0; r < 4; ++r) s += acc[i][j][r];
      s += __shfl_xor(s, 16);
      s += __shfl_xor(s, 32);
      if (quad == 0)
        atomicAdd(&partOut[zh * 256 + bx * TM + wn * WT + j * 16 + laneM], s);
    }
  }

  const long cOff = zb * sC1 + zh * sC2;
#pragma unroll
  for (int i = 0; i < FR; ++i) {
#pragma unroll
    for (int j = 0; j < FR; ++j) {
#pragma unroll
      for (int r = 0; r < 4; ++r) {
        const int lrow = wm * WT + i * 16 + quad * 4 + r;  // row within tile
        const int row = by * TM + lrow;                    // within-batch row
        const int col = bx * TM + wn * WT + j * 16 + laneM;
        const long idx = cOff + (long)row * ldc + col;
        float v = acc[i][j][r];
        if (EPI == 0 || EPI == 1) {
          ((u16*)Cv)[idx] = f2b(v);
        } else if (EPI == 2) {
          ((u16*)Cv)[idx] = f2b(col <= row ? v : 0.0f);
        } else if (EPI == 3) {
          ((u16*)Cv)[idx] = f2b(v / denS[lrow]);
        } else {
          ((float*)Cv)[idx] =
              (zb == 0) ? v + bias[col] + resid[(long)row * ldc + col] : v;
        }
      }
    }
  }
}

// ---------------------------------------------------------------------------
// Convert 7 fp32 2048x2048 tensors -> bf16, dsts contiguous from dst base.
// ---------------------------------------------------------------------------
__global__ __launch_bounds__(256) void convert7(
    const float* __restrict__ s0, const float* __restrict__ s1,
    const float* __restrict__ s2, const float* __restrict__ s3,
    const float* __restrict__ s4, const float* __restrict__ s5,
    const float* __restrict__ s6, u16* __restrict__ dst) {
  long idx = (long)blockIdx.x * 256 + threadIdx.x;  // 0 .. 7*1048576-1
  int seg = (int)(idx >> 20);
  long off = (idx & 1048575) << 2;
  const float* s;
  switch (seg) {
    case 0: s = s0; break; case 1: s = s1; break; case 2: s = s2; break;
    case 3: s = s3; break; case 4: s = s4; break; case 5: s = s5; break;
    default: s = s6;
  }
  float4 v = *(const float4*)(s + off);
  ushort4 o;
  o.x = f2b(v.x); o.y = f2b(v.y); o.z = f2b(v.z); o.w = f2b(v.w);
  *(ushort4*)(dst + (long)seg * 4194304 + off) = o;
}

// pq = phi(Q*(cs+alpha*(kv-cs))), pk = phi(K); phi(x)=x>0?x+1:exp(x).
// cs scan (h<=7 steps over the 8x256 'part' head-sums) computed in-kernel:
// h is uniform per block. 4 elems (consecutive d) per thread.
__global__ __launch_bounds__(256) void pqpk_kernel(
    const u16* __restrict__ Qp, const u16* __restrict__ Kp,
    const u16* __restrict__ kv, const float* __restrict__ part,
    const float* __restrict__ alphaP, const float* __restrict__ betaP,
    u16* __restrict__ pq, u16* __restrict__ pk) {
  long e = ((long)blockIdx.x * 256 + threadIdx.x) * 4;  // (b,h,l,d) packed
  int d = (int)(e & 255), l = (int)((e >> 8) & 255), h = (int)((e >> 16) & 7),
      b = (int)(e >> 19);
  float alpha = *alphaP, beta = *betaP;
  float4 c = {0.f, 0.f, 0.f, 0.f};
  for (int hh = 0; hh < h; ++hh) {  // h uniform per block
    float4 p = *(const float4*)&part[hh * 256 + d];
    c.x = beta * c.x + alpha * (p.x * (1.0f / 2048.0f));
    c.y = beta * c.y + alpha * (p.y * (1.0f / 2048.0f));
    c.z = beta * c.z + alpha * (p.z * (1.0f / 2048.0f));
    c.w = beta * c.w + alpha * (p.w * (1.0f / 2048.0f));
  }
  long pidx = ((long)(b * 256 + l)) * 2048 + h * 256 + d;
  ushort4 q0 = *(const ushort4*)&Qp[pidx];
  ushort4 kk = *(const ushort4*)&Kp[pidx];
  ushort4 kvv = *(const ushort4*)&kv[e];
  ushort4 opq, opk;
#define PQPK1(comp)                                                    \
  {                                                                    \
    float Qv = b2f(q0.comp);                                           \
    float qm = Qv * (c.comp + alpha * (b2f(kvv.comp) - c.comp));       \
    opq.comp = f2b(qm > 0.f ? qm + 1.f : expf(qm));                    \
    float Kv = b2f(kk.comp);                                           \
    opk.comp = f2b(Kv > 0.f ? Kv + 1.f : expf(Kv));                    \
  }
  PQPK1(x) PQPK1(y) PQPK1(z) PQPK1(w)
#undef PQPK1
  *(ushort4*)&pq[e] = opq;
  *(ushort4*)&pk[e] = opk;
}

// Vt[b,h,d,j] = V[b*256+j, h*256+d]  (per-(b,h) 256x256 transpose)
__global__ __launch_bounds__(256) void vtrans_kernel(const u16* __restrict__ Vp,
                                                     u16* __restrict__ Vt) {
  __shared__ u16 tile[32][33];
  int z = blockIdx.z, b = z >> 3, h = z & 7;
  int jT = blockIdx.x * 32, dT = blockIdx.y * 32;
  int tx = threadIdx.x, ty = threadIdx.y;  // (32, 8)
#pragma unroll
  for (int ii = 0; ii < 4; ++ii) {
    int j = jT + ty + ii * 8, d = dT + tx;
    tile[ty + ii * 8][tx] = Vp[(long)(b * 256 + j) * 2048 + h * 256 + d];
  }
  __syncthreads();
#pragma unroll
  for (int ii = 0; ii < 4; ++ii) {
    int d = dT + ty + ii * 8, j = jT + tx;
    Vt[(long)z * 65536 + d * 256 + j] = tile[tx][ty + ii * 8];
  }
}

// LayerNorm over rows of 2048; input = x0 + x1 (split-K partials).
__global__ __launch_bounds__(256) void ln_kernel(
    const float* __restrict__ x0, const float* __restrict__ x1,
    const float* __restrict__ g, const float* __restrict__ bb,
    float* __restrict__ out) {
  int row = blockIdx.x, t = threadIdx.x;
  const float4* xr0 = (const float4*)(x0 + (long)row * 2048);
  const float4* xr1 = (const float4*)(x1 + (long)row * 2048);
  float4 a0 = xr0[t], b0 = xr1[t], a1 = xr0[t + 256], b1 = xr1[t + 256];
  float4 v0, v1;
  v0.x = a0.x + b0.x; v0.y = a0.y + b0.y; v0.z = a0.z + b0.z; v0.w = a0.w + b0.w;
  v1.x = a1.x + b1.x; v1.y = a1.y + b1.y; v1.z = a1.z + b1.z; v1.w = a1.w + b1.w;
  float s = v0.x + v0.y + v0.z + v0.w + v1.x + v1.y + v1.z + v1.w;
  float ss = v0.x * v0.x + v0.y * v0.y + v0.z * v0.z + v0.w * v0.w +
             v1.x * v1.x + v1.y * v1.y + v1.z * v1.z + v1.w * v1.w;
  for (int o = 32; o; o >>= 1) { s += __shfl_xor(s, o); ss += __shfl_xor(ss, o); }
  __shared__ float a1s[4], a2s[4];
  int wave = t >> 6, lane = t & 63;
  if (lane == 0) { a1s[wave] = s; a2s[wave] = ss; }
  __syncthreads();
  s = a1s[0] + a1s[1] + a1s[2] + a1s[3];
  ss = a2s[0] + a2s[1] + a2s[2] + a2s[3];
  float mu = s * (1.f / 2048.f);
  float var = ss * (1.f / 2048.f) - mu * mu;
  float rstd = rsqrtf(var + 1e-5f);
  const float4* g4 = (const float4*)g;
  const float4* b4 = (const float4*)bb;
  float4* orow = (float4*)(out + (long)row * 2048);
  float4 gg = g4[t], bv = b4[t], r;
  r.x = (v0.x - mu) * rstd * gg.x + bv.x;
  r.y = (v0.y - mu) * rstd * gg.y + bv.y;
  r.z = (v0.z - mu) * rstd * gg.z + bv.z;
  r.w = (v0.w - mu) * rstd * gg.w + bv.w;
  orow[t] = r;
  gg = g4[t + 256]; bv = b4[t + 256];
  r.x = (v1.x - mu) * rstd * gg.x + bv.x;
  r.y = (v1.y - mu) * rstd * gg.y + bv.y;
  r.z = (v1.z - mu) * rstd * gg.z + bv.z;
  r.w = (v1.w - mu) * rstd * gg.w + bv.w;
  orow[t + 256] = r;
}

extern "C" void kernel_launch(void* const* d_in, const int* in_sizes, int n_in,
                              void* d_out, int out_size, void* d_ws,
                              size_t ws_size, hipStream_t stream) {
  const float* query = (const float*)d_in[0];
  const float* key = (const float*)d_in[1];
  const float* value = (const float*)d_in[2];
  const float* Wq = (const float*)d_in[3];
  const float* Wk = (const float*)d_in[4];
  const float* Wv = (const float*)d_in[5];
  const float* Wo = (const float*)d_in[6];
  const float* bo = (const float*)d_in[7];
  const float* ln_g = (const float*)d_in[8];
  const float* ln_b = (const float*)d_in[9];
  const float* alphaP = (const float*)d_in[10];
  const float* betaP = (const float*)d_in[11];

  char* ws = (char*)d_ws;
  const long SZ = 8388608;        // bytes of one 2048x2048 bf16 tensor
  const long SE = 4194304;        // elements of one 2048x2048 tensor
  // Workspace liveness (R5 layout, verified against dispatch order):
  //  @0  (3SZ) qb,kb,vb inputs -> dead after proj; x1 (2SZ fp32) reuses @0
  //  @3  (4SZ) Wb: Wq,Wk,Wv dead after proj; Wob @6 lives until Wo GEMM
  //  @7  (3SZ) Qp,Kp,Vp projections
  //  @10 (1SZ) kvb; Ab overwrites it after pqpk
  //  @12 pq, @13 pk -> dead after A GEMM; x0 (2SZ fp32) reuses @12..14
  //  @14 Vt, @15 attnb
  //  @16SZ part (8 KB, atomic-accumulated head sums)
  u16* qb = (u16*)(ws);
  u16* Wb = (u16*)(ws + 3 * SZ);
  u16* Qp = (u16*)(ws + 7 * SZ);
  u16* Kp = (u16*)(ws + 8 * SZ);
  u16* Vp = (u16*)(ws + 9 * SZ);
  u16* kvb = (u16*)(ws + 10 * SZ);
  u16* Ab = kvb;
  u16* pq = (u16*)(ws + 12 * SZ);
  u16* pk = (u16*)(ws + 13 * SZ);
  u16* Vt = (u16*)(ws + 14 * SZ);
  u16* attnb = (u16*)(ws + 15 * SZ);
  u16* Wob = Wb + 3 * SE;
  float* x0 = (float*)(ws + 12 * SZ);
  float* x1 = (float*)(ws);
  float* part = (float*)(ws + 16 * SZ);

  // 0. zero the cs partial-sum accumulator (d_ws is re-poisoned every call)
  hipMemsetAsync(part, 0, 8 * 256 * sizeof(float), stream);

  // 1. fp32 -> bf16 converts (7 tensors)
  convert7<<<28672, 256, 0, stream>>>(query, key, value, Wq, Wk, Wv, Wo, qb);

  // 2. Q/K/V projections (unsplit; occupancy is register-limited, R6)
  gemm_bt<0, 32, 128><<<dim3(16, 16, 3), 256, 0, stream>>>(
      qb, 2048, SE, 0L, Wb, 2048, SE, 0L, (void*)Qp, 2048, SE, 0L, 2048, 1,
      nullptr, nullptr, nullptr);

  // 3. kv[b,h,l,m] = sum_d K[b,h,l,d] V[b,h,m,d], TM=64 grid (4,4,64)
  //    = 4 blocks/CU for latency hiding; + fused head-sum atomics
  gemm_bt<1, 64, 64><<<dim3(4, 4, 64), 256, 0, stream>>>(
      Kp, 2048, 524288L, 256L, Vp, 2048, 524288L, 256L, (void*)kvb, 256,
      524288L, 65536L, 256, 8, nullptr, nullptr, part);

  // 4. pq/pk with in-kernel cs scan
  pqpk_kernel<<<4096, 256, 0, stream>>>(Qp, Kp, kvb, part, alphaP, betaP, pq,
                                        pk);

  // 5. A = pq @ pk^T causal, TM=64; upper-tri blocks early-exit (10/16 work)
  gemm_bt<2, 64, 64><<<dim3(4, 4, 64), 256, 0, stream>>>(
      pq, 256, 524288L, 65536L, pk, 256, 524288L, 65536L, (void*)Ab, 256,
      524288L, 65536L, 256, 8, nullptr, nullptr, nullptr);

  // 6. V transpose per (b,h): Vt[d,j] = V[j,d]
  vtrans_kernel<<<dim3(8, 8, 64), dim3(32, 8), 0, stream>>>(Vp, Vt);

  // 7. attn = (A @ V)/den, TM=64, K clamped to (by+1)*64, den fused
  gemm_bt<3, 64, 64><<<dim3(4, 4, 64), 256, 0, stream>>>(
      Ab, 256, 524288L, 65536L, Vt, 256, 524288L, 65536L, (void*)attnb, 2048,
      524288L, 256L, 256, 8, nullptr, nullptr, nullptr);

  // 8. x = attn @ Wo^T (+ bo + query on z=0), split-K=2.
  //    sC1 = (x1 - x0) in floats = -12*SZ/4: zb=0 -> x0 (@12SZ), zb=1 -> x1 (@0)
  gemm_bt<4, 32, 128><<<dim3(16, 16, 2), 256, 0, stream>>>(
      attnb, 2048, 1024L, 0L, Wob, 2048, 1024L, 0L, (void*)x0, 2048,
      -25165824L, 0L, 1024, 1, bo, query, nullptr);

  // 9. LayerNorm(x0 + x1) -> d_out
  ln_kernel<<<2048, 256, 0, stream>>>(x0, x1, ln_g, ln_b, (float*)d_out);
}